// Round 7
// baseline (1667.751 us; speedup 1.0000x reference)
//
#include <hip/hip_runtime.h>
#include <hip/hip_bf16.h>

typedef __attribute__((ext_vector_type(4))) float f32x4;
typedef __attribute__((ext_vector_type(8))) short short8;

#define DEVFN __device__ __forceinline__

static constexpr int Bn = 16, Tn = 512, Sn = 512, Vn = 10000, En = 512, Hn = 1024, Ln = 6;
static constexpr int Mn = Bn * Tn;  // 8192 token rows
static constexpr float kScale = 0.70710678118654752440f;

DEVFN float bf2f(__hip_bfloat16 x) { return __bfloat162float(x); }
DEVFN __hip_bfloat16 f2bf(float x) { return __float2bfloat16(x); }

struct bf16x4 { __hip_bfloat16 x, y, z, w; };

// async global -> LDS, 16B per lane (wave-uniform LDS base + lane*16 layout)
DEVFN void gload_lds16(const short* g, short* l) {
    __builtin_amdgcn_global_load_lds((const __attribute__((address_space(1))) void*)g,
                                     (__attribute__((address_space(3))) void*)l, 16, 0, 0);
}

// ---------------- small prep kernels ----------------

__global__ void padfill_kernel(__hip_bfloat16* p) {
    p[threadIdx.x] = f2bf(1.0f);  // PAD_VAL as float, per torch code
}

// embedded[b,t,:] = tok_emb[tgt[b,t],:] + pos_emb[t,:]  (bf16)
// embA = kScale*(embedded + b_ah2e)                      (bf16)
__global__ void embed_kernel(const int* __restrict__ tgt, const float* __restrict__ tok,
                             const float* __restrict__ pos, const float* __restrict__ bah,
                             __hip_bfloat16* __restrict__ out, __hip_bfloat16* __restrict__ outA) {
    int row = blockIdx.x;              // 0..8191
    int t = row & (Tn - 1);
    int v = tgt[row];
    const float* tr = tok + (long)v * En;
    const float* pr = pos + (long)t * En;
    int e = threadIdx.x * 4;           // block 128 covers 512
    float4 a = *(const float4*)(tr + e);
    float4 b = *(const float4*)(pr + e);
    float4 bb = *(const float4*)(bah + e);
    bf16x4 o{f2bf(a.x + b.x), f2bf(a.y + b.y), f2bf(a.z + b.z), f2bf(a.w + b.w)};
    *(bf16x4*)(out + (long)row * En + e) = o;
    bf16x4 oa{f2bf(kScale * (a.x + b.x + bb.x)), f2bf(kScale * (a.y + b.y + bb.y)),
              f2bf(kScale * (a.z + b.z + bb.z)), f2bf(kScale * (a.w + b.w + bb.w))};
    *(bf16x4*)(outA + (long)row * En + e) = oa;
}

// dst[c][r] = bf16(src[r][c]); src is [R][C] f32. grid(ceil(C/32), ceil(R/32), Z), block(32,8)
__global__ void transpose_f32_bf16(const float* __restrict__ src, __hip_bfloat16* __restrict__ dst,
                                   int R, int C, long sZi, long sZo) {
    __shared__ float tile[32][33];
    src += (long)blockIdx.z * sZi;
    dst += (long)blockIdx.z * sZo;
    int c0 = blockIdx.x * 32, r0 = blockIdx.y * 32;
    for (int i = threadIdx.y; i < 32; i += 8) {
        int r = r0 + i, c = c0 + threadIdx.x;
        tile[i][threadIdx.x] = (r < R && c < C) ? src[(long)r * C + c] : 0.f;
    }
    __syncthreads();
    for (int i = threadIdx.y; i < 32; i += 8) {
        int c = c0 + i, r = r0 + threadIdx.x;
        if (c < C && r < R) dst[(long)c * R + r] = f2bf(tile[threadIdx.x][i]);
    }
}

// f32 -> bf16 convert with scale (n divisible by 4)
__global__ void convert_bf16_kernel(const float* __restrict__ src, __hip_bfloat16* __restrict__ dst,
                                    long n4, float sc) {
    long i = (long)blockIdx.x * blockDim.x + threadIdx.x;
    if (i >= n4) return;
    long j = i * 4;
    float4 v = *(const float4*)(src + j);
    bf16x4 o{f2bf(v.x * sc), f2bf(v.y * sc), f2bf(v.z * sc), f2bf(v.w * sc)};
    *(bf16x4*)(dst + j) = o;
}

// conv weight pack for layer lbase+blockIdx.z, a/g interleaved in 16-col blocks:
// packed col c: grp=c>>5, w=c&31; o = w<16 ? grp*16+w : H + grp*16 + (w-16)
// wp[z*stride + c][tap*H+i] = bf16(conv_w[l][o][i][tap]).  grid(12, 2048, nl), block 256.
__global__ void wpack_kernel(const float* __restrict__ convw, __hip_bfloat16* __restrict__ wp,
                             int lbase, long zstride) {
    int kk = blockIdx.x * 256 + threadIdx.x;  // 0..3071
    int c = blockIdx.y;                        // 0..2047 packed col
    int l = lbase + blockIdx.z;
    int grp = c >> 5, w = c & 31;
    int o = (w < 16) ? grp * 16 + w : Hn + grp * 16 + (w - 16);
    int i = kk & (Hn - 1);
    int tap = kk >> 10;
    long base = ((long)(l * 2 * Hn + o)) * (Hn * 3);
    wp[(long)blockIdx.z * zstride + (long)c * (3 * Hn) + kk] = f2bf(convw[base + (long)i * 3 + tap]);
}

// ---------------- fused energy + softmax ----------------
// Per block: 128 t-rows x full S=512 cols of one batch. acc = conved@encAHs^T (K=1024)
//            + embA@encc^T (K=512), then block row-softmax -> attnbf (+f32 last layer).
// 8 waves 2Mx4N (wave = 64 rows x 128 cols, acc[4][8]); BK=32 double-buffered,
// counted vmcnt(5) (gemm256's verified pattern). grid(Tn/128, Bn).
template <bool LAST>
__global__ __launch_bounds__(512) void attn_fused(
    const __hip_bfloat16* __restrict__ conved, const __hip_bfloat16* __restrict__ encAHs,
    const __hip_bfloat16* __restrict__ embA, const __hip_bfloat16* __restrict__ encc,
    __hip_bfloat16* __restrict__ attn_bf, float* __restrict__ attn_f32) {
    __shared__ alignas(16) short Asl[2][128 * 32];
    __shared__ alignas(16) short Bsl[2][512 * 32];
    __shared__ float redm[2][64][4];
    __shared__ float reds[2][64][4];
    const int tid = threadIdx.x;
    const int lane = tid & 63;
    const int wid = tid >> 6;
    const int wr = wid >> 2, wc = wid & 3;     // 2M x 4N
    const int m0 = blockIdx.x * 128;
    const int z = blockIdx.y;
    const long grow0 = (long)z * Tn + m0;       // global row base
    const short* A1 = (const short*)conved + grow0 * Hn;
    const short* B1 = (const short*)encAHs + (long)z * Sn * Hn;
    const short* A2 = (const short*)embA + grow0 * En;
    const short* B2 = (const short*)encc + (long)z * Sn * En;
    constexpr int NT1 = Hn / 32, NT2 = En / 32, NT = NT1 + NT2;

    f32x4 acc[4][8] = {};

    const int sr = tid >> 2;            // staging row 0..127
    const int sc = (tid & 3) * 8;       // col offset (shorts)

    auto stage = [&](int buf, int t) {
        const short *Ag, *Bg; int stA, k0;
        if (t < NT1) { Ag = A1; Bg = B1; stA = Hn; k0 = t * 32; }
        else         { Ag = A2; Bg = B2; stA = En; k0 = (t - NT1) * 32; }
        gload_lds16(Ag + (long)sr * stA + k0 + sc, &Asl[buf][sr * 32 + sc]);
#pragma unroll
        for (int j = 0; j < 4; ++j) {
            int rb = j * 128 + sr;
            gload_lds16(Bg + (long)rb * stA + k0 + sc, &Bsl[buf][rb * 32 + sc]);
        }
    };

    const int rsel = lane & 15, hi8 = (lane >> 4) * 8;

    stage(0, 0);
    for (int t = 0; t < NT; ++t) {
        const int cur = t & 1;
        if (t + 1 < NT) {
            stage(cur ^ 1, t + 1);
            asm volatile("s_waitcnt vmcnt(5)" ::: "memory");   // tile t's 5 loads done
        } else {
            asm volatile("s_waitcnt vmcnt(0)" ::: "memory");
        }
        __builtin_amdgcn_s_barrier();
        __builtin_amdgcn_sched_barrier(0);
        short8 af[4], bgv[8];
#pragma unroll
        for (int mi = 0; mi < 4; ++mi)
            af[mi] = *(const short8*)&Asl[cur][(wr * 64 + mi * 16 + rsel) * 32 + hi8];
#pragma unroll
        for (int ni = 0; ni < 8; ++ni)
            bgv[ni] = *(const short8*)&Bsl[cur][(wc * 128 + ni * 16 + rsel) * 32 + hi8];
        __builtin_amdgcn_s_setprio(1);
#pragma unroll
        for (int mi = 0; mi < 4; ++mi)
#pragma unroll
            for (int ni = 0; ni < 8; ++ni)
                acc[mi][ni] = __builtin_amdgcn_mfma_f32_16x16x32_bf16(af[mi], bgv[ni], acc[mi][ni], 0, 0, 0);
        __builtin_amdgcn_s_setprio(0);
        __builtin_amdgcn_s_barrier();
        __builtin_amdgcn_sched_barrier(0);
    }

    // ---- block row-softmax over 512 cols ----
    const int h = lane >> 4;
    float Mx[4][4];
#pragma unroll
    for (int mi = 0; mi < 4; ++mi)
#pragma unroll
        for (int q = 0; q < 4; ++q) {
            float m = acc[mi][0][q];
#pragma unroll
            for (int ni = 1; ni < 8; ++ni) m = fmaxf(m, acc[mi][ni][q]);
            m = fmaxf(m, __shfl_xor(m, 1));
            m = fmaxf(m, __shfl_xor(m, 2));
            m = fmaxf(m, __shfl_xor(m, 4));
            m = fmaxf(m, __shfl_xor(m, 8));
            Mx[mi][q] = m;   // max over this wave's 128 cols
        }
    if (rsel == 0) {
#pragma unroll
        for (int mi = 0; mi < 4; ++mi)
#pragma unroll
            for (int q = 0; q < 4; ++q)
                redm[wr][mi * 16 + h * 4 + q][wc] = Mx[mi][q];
    }
    __syncthreads();
    float Sv[4][4];
#pragma unroll
    for (int mi = 0; mi < 4; ++mi)
#pragma unroll
        for (int q = 0; q < 4; ++q) {
            const float* rm = redm[wr][mi * 16 + h * 4 + q];
            float m = fmaxf(fmaxf(rm[0], rm[1]), fmaxf(rm[2], rm[3]));
            float s = 0.f;
#pragma unroll
            for (int ni = 0; ni < 8; ++ni) {
                float e = __expf(acc[mi][ni][q] - m);
                acc[mi][ni][q] = e;
                s += e;
            }
            s += __shfl_xor(s, 1);
            s += __shfl_xor(s, 2);
            s += __shfl_xor(s, 4);
            s += __shfl_xor(s, 8);
            Sv[mi][q] = s;
        }
    if (rsel == 0) {
#pragma unroll
        for (int mi = 0; mi < 4; ++mi)
#pragma unroll
            for (int q = 0; q < 4; ++q)
                reds[wr][mi * 16 + h * 4 + q][wc] = Sv[mi][q];
    }
    __syncthreads();
#pragma unroll
    for (int mi = 0; mi < 4; ++mi)
#pragma unroll
        for (int q = 0; q < 4; ++q) {
            const float* rs = reds[wr][mi * 16 + h * 4 + q];
            float inv = 1.f / (rs[0] + rs[1] + rs[2] + rs[3]);
            long gr = grow0 + wr * 64 + mi * 16 + h * 4 + q;
#pragma unroll
            for (int ni = 0; ni < 8; ++ni) {
                int col = wc * 128 + ni * 16 + rsel;
                float v = acc[mi][ni][q] * inv;
                attn_bf[gr * Sn + col] = f2bf(v);
                if (LAST) attn_f32[gr * Sn + col] = v;
            }
        }
}

// ---------------- 128x128 2-phase GEMM ----------------
// C[M,N] = A[M,K] @ Bw[N,K]^T.  EPI: 0: x=acc+bias; 2: x=((acc+bias+R1)*s1+R2)*s2.
template <int EPI, bool OUTF32, bool NBOUND>
__global__ __launch_bounds__(256) void gemm_bf16(
    const __hip_bfloat16* __restrict__ A, const __hip_bfloat16* __restrict__ Bw,
    const float* __restrict__ bias, void* __restrict__ Cout,
    const __hip_bfloat16* __restrict__ R1, const __hip_bfloat16* __restrict__ R2,
    const __hip_bfloat16* __restrict__ padrow,
    int M, int N, int K, long aZ, long bZ, long cZ, float s1, float s2) {
    __shared__ alignas(16) short As[2][128 * 32];
    __shared__ alignas(16) short Bs[2][128 * 32];
    const int tid = threadIdx.x;
    const int lane = tid & 63;
    const int wid = tid >> 6;
    const int wr = wid >> 1, wc = wid & 1;
    const int m0 = blockIdx.y * 128, n0 = blockIdx.x * 128;
    const short* Ag = (const short*)A + (long)blockIdx.z * aZ;
    const short* Bg = (const short*)Bw + (long)blockIdx.z * bZ;
    const short* pad = (const short*)padrow;

    f32x4 acc[4][4] = {};

    const int rc = tid >> 2;
    const int k8 = (tid & 3) * 8;

    auto stage = [&](int buf, int k0) {
#pragma unroll
        for (int j = 0; j < 2; ++j) {
            int r = rc + j * 64;
            const short* asrc = Ag + (long)(m0 + r) * K + k0 + k8;
            gload_lds16(asrc, &As[buf][r * 32 + k8]);
            int n = n0 + r;
            const short* bsrc = (NBOUND && n >= N) ? (pad + k8) : (Bg + (long)n * K + k0 + k8);
            gload_lds16(bsrc, &Bs[buf][r * 32 + k8]);
        }
    };

    stage(0, 0);
    __syncthreads();

    int cur = 0;
    for (int k0 = 0; k0 < K; k0 += 32) {
        if (k0 + 32 < K) stage(cur ^ 1, k0 + 32);
        const int rsel = lane & 15, hi = (lane >> 4) * 8;
        short8 af[4], bg[4];
#pragma unroll
        for (int mi = 0; mi < 4; ++mi)
            af[mi] = *(const short8*)&As[cur][(wr * 64 + mi * 16 + rsel) * 32 + hi];
#pragma unroll
        for (int ni = 0; ni < 4; ++ni)
            bg[ni] = *(const short8*)&Bs[cur][(wc * 64 + ni * 16 + rsel) * 32 + hi];
#pragma unroll
        for (int mi = 0; mi < 4; ++mi)
#pragma unroll
            for (int ni = 0; ni < 4; ++ni)
                acc[mi][ni] = __builtin_amdgcn_mfma_f32_16x16x32_bf16(af[mi], bg[ni], acc[mi][ni], 0, 0, 0);
        __syncthreads();
        cur ^= 1;
    }

    const int rsel = lane & 15, rg = (lane >> 4) * 4;
    float* Cf = (float*)Cout + (long)blockIdx.z * cZ;
    __hip_bfloat16* Cb = (__hip_bfloat16*)Cout + (long)blockIdx.z * cZ;
    const __hip_bfloat16* R1z = R1 + (long)blockIdx.z * cZ;
    const __hip_bfloat16* R2z = R2 + (long)blockIdx.z * cZ;
#pragma unroll
    for (int ni = 0; ni < 4; ++ni) {
        int col = n0 + wc * 64 + ni * 16 + rsel;
        if (NBOUND && col >= N) continue;
        float bi = bias ? bias[col] : 0.f;
#pragma unroll
        for (int mi = 0; mi < 4; ++mi) {
            int row = m0 + wr * 64 + mi * 16 + rg;
            f32x4 v = acc[mi][ni];
#pragma unroll
            for (int q = 0; q < 4; ++q) {
                long idx = (long)(row + q) * N + col;
                float x = v[q] + bi;
                if (EPI >= 1) x = (x + bf2f(R1z[idx])) * s1;
                if (EPI >= 2) x = (x + bf2f(R2z[idx])) * s2;
                if (OUTF32) Cf[idx] = x;
                else Cb[idx] = f2bf(x);
            }
        }
    }
}

// ---------------- 256x256 deep-pipeline GEMM (conv + fc_out) ----------------
template <bool OUTF32, bool GLUE, bool IM2COL, bool NBOUND>
__global__ __launch_bounds__(512, 2) void gemm256(
    const __hip_bfloat16* __restrict__ A, const __hip_bfloat16* __restrict__ Bw,
    const float* __restrict__ bias, void* __restrict__ Cout,
    const __hip_bfloat16* __restrict__ padrow, int M, int N, int K) {
    __shared__ alignas(16) short As[2][256 * 64];
    __shared__ alignas(16) short Bs[2][256 * 64];
    const int tid = threadIdx.x;
    const int lane = tid & 63;
    const int wid = tid >> 6;
    const int wr = wid >> 2, wc = wid & 3;
    const int nwg = gridDim.x * gridDim.y;
    const int orig = blockIdx.y * gridDim.x + blockIdx.x;
    const int qd = nwg >> 3, rd = nwg & 7, xc = orig & 7, loc = orig >> 3;
    const int bid = (xc < rd ? xc * (qd + 1) : rd * (qd + 1) + (xc - rd) * qd) + loc;
    const int n0 = (bid % gridDim.x) * 256, m0 = (bid / gridDim.x) * 256;
    const short* Ag = (const short*)A;
    const short* Bg = (const short*)Bw;
    const short* pad = (const short*)padrow;

    f32x4 acc[8][4] = {};

    const int srow_l = tid >> 3;
    const int scol = ((tid & 7) ^ (srow_l & 7)) * 8;
    const int sdst = (tid >> 3) * 64 + (tid & 7) * 8;

    auto stage = [&](int buf, int kt) {
        const int k0 = kt * 64;
#pragma unroll
        for (int j = 0; j < 4; ++j) {
            const int row = j * 64 + srow_l;
            const short* asrc;
            if (IM2COL) {
                int m = m0 + row;
                int t = m & (Tn - 1);
                int tap = k0 >> 10;
                int tau = t - 2 + tap;
                int kcol = (k0 & (Hn - 1)) + scol;
                asrc = (tau >= 0) ? (Ag + (long)(m - 2 + tap) * Hn + kcol) : (pad + scol);
            } else {
                asrc = Ag + (long)(m0 + row) * K + k0 + scol;
            }
            gload_lds16(asrc, &As[buf][j * 4096 + sdst]);
            int n = n0 + row;
            const short* bsrc = (NBOUND && n >= N) ? (pad + scol) : (Bg + (long)n * K + k0 + scol);
            gload_lds16(bsrc, &Bs[buf][j * 4096 + sdst]);
        }
    };

    const int rsel = lane & 15, hi = (lane >> 4) * 8;
    const int xorc = (rsel & 7) << 3;

    stage(0, 0);
    const int NT = K >> 6;
    for (int t = 0; t < NT; ++t) {
        const int cur = t & 1;
        if (t + 1 < NT) {
            stage(cur ^ 1, t + 1);
            asm volatile("s_waitcnt vmcnt(8)" ::: "memory");
        } else {
            asm volatile("s_waitcnt vmcnt(0)" ::: "memory");
        }
        __builtin_amdgcn_s_barrier();
        __builtin_amdgcn_sched_barrier(0);
        short8 bg[2][2][2];
#pragma unroll
        for (int nh = 0; nh < 2; ++nh)
#pragma unroll
            for (int i = 0; i < 2; ++i) {
                const int row = wc * 64 + nh * 32 + i * 16 + rsel;
#pragma unroll
                for (int ks = 0; ks < 2; ++ks)
                    bg[nh][i][ks] = *(const short8*)&Bs[cur][row * 64 + ((ks * 32 + hi) ^ xorc)];
            }
#pragma unroll
        for (int mh = 0; mh < 2; ++mh) {
            short8 af[4][2];
#pragma unroll
            for (int i = 0; i < 4; ++i) {
                const int row = wr * 128 + mh * 64 + i * 16 + rsel;
#pragma unroll
                for (int ks = 0; ks < 2; ++ks)
                    af[i][ks] = *(const short8*)&As[cur][row * 64 + ((ks * 32 + hi) ^ xorc)];
            }
            __builtin_amdgcn_s_setprio(1);
#pragma unroll
            for (int nh = 0; nh < 2; ++nh)
#pragma unroll
                for (int i = 0; i < 4; ++i)
#pragma unroll
                    for (int jn = 0; jn < 2; ++jn)
#pragma unroll
                        for (int ks = 0; ks < 2; ++ks)
                            acc[mh * 4 + i][nh * 2 + jn] = __builtin_amdgcn_mfma_f32_16x16x32_bf16(
                                af[i][ks], bg[nh][jn][ks], acc[mh * 4 + i][nh * 2 + jn], 0, 0, 0);
            __builtin_amdgcn_s_setprio(0);
            __builtin_amdgcn_sched_barrier(0);
        }
        __builtin_amdgcn_s_barrier();
        __builtin_amdgcn_sched_barrier(0);
    }

    const int rg = (lane >> 4) * 4;
    if (GLUE) {
        __hip_bfloat16* Cb = (__hip_bfloat16*)Cout;
        const int No = N >> 1;
#pragma unroll
        for (int p = 0; p < 2; ++p) {
            int jcol = ((n0 + wc * 64) >> 1) + p * 16 + rsel;
            float ba = bias[jcol];
            float bgv = bias[Hn + jcol];
#pragma unroll
            for (int mi = 0; mi < 8; ++mi) {
                int row = m0 + wr * 128 + mi * 16 + rg;
                f32x4 va = acc[mi][2 * p], vg = acc[mi][2 * p + 1];
#pragma unroll
                for (int q = 0; q < 4; ++q) {
                    float a = va[q] + ba;
                    float g = vg[q] + bgv;
                    Cb[(long)(row + q) * No + jcol] = f2bf(a * (1.f / (1.f + __expf(-g))));
                }
            }
        }
        return;
    }
    float* Cf = (float*)Cout;
    __hip_bfloat16* Cb = (__hip_bfloat16*)Cout;
#pragma unroll
    for (int ni = 0; ni < 4; ++ni) {
        int col = n0 + wc * 64 + ni * 16 + rsel;
        if (NBOUND && col >= N) continue;
        float bi = bias ? bias[col] : 0.f;
#pragma unroll
        for (int mi = 0; mi < 8; ++mi) {
            int row = m0 + wr * 128 + mi * 16 + rg;
            f32x4 v = acc[mi][ni];
#pragma unroll
            for (int q = 0; q < 4; ++q) {
                long idx = (long)(row + q) * N + col;
                float x = v[q] + bi;
                if (OUTF32) Cf[idx] = x;
                else Cb[idx] = f2bf(x);
            }
        }
    }
}

// ---------------- launcher ----------------

extern "C" void kernel_launch(void* const* d_in, const int* in_sizes, int n_in,
                              void* d_out, int out_size, void* d_ws, size_t ws_size,
                              hipStream_t stream) {
    const int* tgt = (const int*)d_in[0];
    const float* enc_conved = (const float*)d_in[1];
    const float* enc_combined = (const float*)d_in[2];
    const float* tok_emb = (const float*)d_in[3];
    const float* pos_emb = (const float*)d_in[4];
    const float* w_e2h = (const float*)d_in[5];
    const float* b_e2h = (const float*)d_in[6];
    const float* w_h2e = (const float*)d_in[7];
    const float* b_h2e = (const float*)d_in[8];
    const float* w_ah2e = (const float*)d_in[9];
    const float* b_ah2e = (const float*)d_in[10];
    const float* w_ae2h = (const float*)d_in[11];
    const float* b_ae2h = (const float*)d_in[12];
    const float* w_fc = (const float*)d_in[13];
    const float* b_fc = (const float*)d_in[14];
    const float* conv_w = (const float*)d_in[15];
    const float* conv_b = (const float*)d_in[16];

    char* ws = (char*)d_ws;
    size_t off = 0;
    auto alloc = [&](size_t bytes) { size_t r = off; off = (off + bytes + 255) & ~(size_t)255; return r; };
    __hip_bfloat16* emb    = (__hip_bfloat16*)(ws + alloc((size_t)Mn * En * 2));
    __hip_bfloat16* embA   = (__hip_bfloat16*)(ws + alloc((size_t)Mn * En * 2));
    __hip_bfloat16* convin = (__hip_bfloat16*)(ws + alloc((size_t)Mn * Hn * 2));
    __hip_bfloat16* conved = (__hip_bfloat16*)(ws + alloc((size_t)Mn * Hn * 2));
    __hip_bfloat16* attnbf = (__hip_bfloat16*)(ws + alloc((size_t)Mn * Sn * 2));
    __hip_bfloat16* encm   = (__hip_bfloat16*)(ws + alloc((size_t)Bn * Sn * En * 2));
    __hip_bfloat16* wT_e2h = (__hip_bfloat16*)(ws + alloc((size_t)Hn * En * 2));
    __hip_bfloat16* wT_h2e = (__hip_bfloat16*)(ws + alloc((size_t)En * Hn * 2));
    __hip_bfloat16* wT_ae2h= (__hip_bfloat16*)(ws + alloc((size_t)Hn * En * 2));
    __hip_bfloat16* wbAHs  = (__hip_bfloat16*)(ws + alloc((size_t)Hn * En * 2));   // kScale * w_ah2e, [H][E]
    __hip_bfloat16* wT_fc  = (__hip_bfloat16*)(ws + alloc((size_t)Vn * En * 2));
    __hip_bfloat16* encc   = (__hip_bfloat16*)(ws + alloc((size_t)Bn * Sn * En * 2));
    __hip_bfloat16* encAHs = (__hip_bfloat16*)(ws + alloc((size_t)Bn * Sn * Hn * 2));
    __hip_bfloat16* encCW  = (__hip_bfloat16*)(ws + alloc((size_t)Bn * Hn * Sn * 2));
    __hip_bfloat16* padrow = (__hip_bfloat16*)(ws + alloc(256));
    // wpack last: all-6-layers if workspace allows, else single-layer reused
    const size_t W1 = (size_t)2 * Hn * 3 * Hn * 2;   // 12.6 MB per layer
    bool packAll = (off + 6 * W1 + 256 <= ws_size);
    __hip_bfloat16* wpack = (__hip_bfloat16*)(ws + alloc(packAll ? 6 * W1 : W1));
    __hip_bfloat16* tmpE = conved;  // overlay: conved dead after last update GEMM

    float* out = (float*)d_out;
    float* attn_out = out + (long)Mn * Vn;
    const long bSq = (long)Sn * Sn;
    const long bSH = (long)Sn * Hn;

    dim3 tb(32, 8);
    const __hip_bfloat16* nb = nullptr;

    // ---- prep ----
    padfill_kernel<<<1, 128, 0, stream>>>(padrow);
    embed_kernel<<<Mn, 128, 0, stream>>>(tgt, tok_emb, pos_emb, b_ah2e, emb, embA);
    transpose_f32_bf16<<<dim3(Hn / 32, En / 32, 1), tb, 0, stream>>>(w_e2h, wT_e2h, En, Hn, 0, 0);
    transpose_f32_bf16<<<dim3(En / 32, Hn / 32, 1), tb, 0, stream>>>(w_h2e, wT_h2e, Hn, En, 0, 0);
    transpose_f32_bf16<<<dim3(Hn / 32, En / 32, 1), tb, 0, stream>>>(w_ae2h, wT_ae2h, En, Hn, 0, 0);
    transpose_f32_bf16<<<dim3((Vn + 31) / 32, En / 32, 1), tb, 0, stream>>>(w_fc, wT_fc, En, Vn, 0, 0);
    convert_bf16_kernel<<<((long)Hn * En / 4 + 255) / 256, 256, 0, stream>>>(w_ah2e, wbAHs, (long)Hn * En / 4, kScale);
    convert_bf16_kernel<<<((long)Bn * Sn * En / 4 + 255) / 256, 256, 0, stream>>>(enc_conved, encc, (long)Bn * Sn * En / 4, 1.f);
    convert_bf16_kernel<<<((long)Bn * Sn * En / 4 + 255) / 256, 256, 0, stream>>>(enc_combined, encm, (long)Bn * Sn * En / 4, 1.f);
    if (packAll)
        wpack_kernel<<<dim3(3 * Hn / 256, 2 * Hn, Ln), 256, 0, stream>>>(conv_w, wpack, 0, (long)2 * Hn * 3 * Hn);

    // encAHs[b][s][h] = encc[b] @ (kScale*w_ah2e)^T   (layer-invariant, scale folded)
    gemm_bf16<0, false, false><<<dim3(Hn / 128, Sn / 128, Bn), 256, 0, stream>>>(
        encc, wbAHs, nullptr, encAHs, nb, nb, padrow, Sn, Hn, En, bSq, 0, bSH, 1.f, 1.f);
    // encCW[b][h][s] = (enc_combined[b] @ w_ae2h)^T
    gemm_bf16<0, false, false><<<dim3(Sn / 128, Hn / 128, Bn), 256, 0, stream>>>(
        wT_ae2h, encm, nullptr, encCW, nb, nb, padrow, Hn, Sn, En, 0, bSq, bSH, 1.f, 1.f);
    // conv_input = embedded @ emb2hid + b       [8192,1024]
    gemm_bf16<0, false, false><<<dim3(Hn / 128, Mn / 128, 1), 256, 0, stream>>>(
        emb, wT_e2h, b_e2h, convin, nb, nb, padrow, Mn, Hn, En, 0, 0, 0, 1.f, 1.f);

    for (int l = 0; l < Ln; ++l) {
        __hip_bfloat16* wpl = wpack + (packAll ? (size_t)l * (2 * Hn) * (3 * Hn) : 0);
        if (!packAll)
            wpack_kernel<<<dim3(3 * Hn / 256, 2 * Hn, 1), 256, 0, stream>>>(conv_w, wpack, l, 0);
        // conved = GLU(im2col(conv_input) @ wpack^T + conv_b[l])   [8192,1024] fused
        gemm256<false, true, true, false><<<dim3(2 * Hn / 256, Mn / 256, 1), 512, 0, stream>>>(
            convin, wpl, conv_b + (long)l * 2 * Hn, conved, padrow, Mn, 2 * Hn, 3 * Hn);
        // attention = softmax(conved@encAHs^T + embA@encc^T)  -> attnbf (+f32 last layer)
        if (l == Ln - 1)
            attn_fused<true><<<dim3(Tn / 128, Bn), 512, 0, stream>>>(conved, encAHs, embA, encc, attnbf, attn_out);
        else
            attn_fused<false><<<dim3(Tn / 128, Bn), 512, 0, stream>>>(conved, encAHs, embA, encc, attnbf, nullptr);
        // conv_input = ((attn @ encCW + b_ae2h + conved)*s + conv_input)*s
        gemm_bf16<2, false, false><<<dim3(Hn / 128, Tn / 128, Bn), 256, 0, stream>>>(
            attnbf, encCW, b_ae2h, convin, conved, convin, padrow,
            Tn, Hn, Sn, bSq, bSH, (long)Tn * Hn, kScale, kScale);
    }

    // conved = conv_input @ hid2emb + b   [8192,512]  (tmpE overlays conved)
    gemm_bf16<0, false, false><<<dim3(En / 128, Mn / 128, 1), 256, 0, stream>>>(
        convin, wT_h2e, b_h2e, tmpE, nb, nb, padrow, Mn, En, Hn, 0, 0, 0, 1.f, 1.f);
    // output = conved @ fc_out + b        [8192,10000] f32, N-bounded  (256² pipeline)
    gemm256<true, false, false, true><<<dim3((Vn + 255) / 256, Mn / 256, 1), 512, 0, stream>>>(
        tmpE, wT_fc, b_fc, out, padrow, Mn, Vn, En);
}

// Round 8
// 1495.895 us; speedup vs baseline: 1.1149x; 1.1149x over previous
//
#include <hip/hip_runtime.h>
#include <hip/hip_bf16.h>

typedef __attribute__((ext_vector_type(4))) float f32x4;
typedef __attribute__((ext_vector_type(8))) short short8;

#define DEVFN __device__ __forceinline__

static constexpr int Bn = 16, Tn = 512, Sn = 512, Vn = 10000, En = 512, Hn = 1024, Ln = 6;
static constexpr int Mn = Bn * Tn;  // 8192 token rows
static constexpr float kScale = 0.70710678118654752440f;

DEVFN float bf2f(__hip_bfloat16 x) { return __bfloat162float(x); }
DEVFN __hip_bfloat16 f2bf(float x) { return __float2bfloat16(x); }

struct bf16x4 { __hip_bfloat16 x, y, z, w; };

// async global -> LDS, 16B per lane (wave-uniform LDS base + lane*16 layout)
DEVFN void gload_lds16(const short* g, short* l) {
    __builtin_amdgcn_global_load_lds((const __attribute__((address_space(1))) void*)g,
                                     (__attribute__((address_space(3))) void*)l, 16, 0, 0);
}

// ---------------- small prep kernels ----------------

__global__ void padfill_kernel(__hip_bfloat16* p) {
    p[threadIdx.x] = f2bf(1.0f);  // PAD_VAL as float, per torch code
}

// embedded[b,t,:] = tok_emb[tgt[b,t],:] + pos_emb[t,:]  (bf16)
// embA = kScale*(embedded + b_ah2e)                      (bf16, for embE precompute)
__global__ void embed_kernel(const int* __restrict__ tgt, const float* __restrict__ tok,
                             const float* __restrict__ pos, const float* __restrict__ bah,
                             __hip_bfloat16* __restrict__ out, __hip_bfloat16* __restrict__ outA) {
    int row = blockIdx.x;              // 0..8191
    int t = row & (Tn - 1);
    int v = tgt[row];
    const float* tr = tok + (long)v * En;
    const float* pr = pos + (long)t * En;
    int e = threadIdx.x * 4;           // block 128 covers 512
    float4 a = *(const float4*)(tr + e);
    float4 b = *(const float4*)(pr + e);
    float4 bb = *(const float4*)(bah + e);
    bf16x4 o{f2bf(a.x + b.x), f2bf(a.y + b.y), f2bf(a.z + b.z), f2bf(a.w + b.w)};
    *(bf16x4*)(out + (long)row * En + e) = o;
    bf16x4 oa{f2bf(kScale * (a.x + b.x + bb.x)), f2bf(kScale * (a.y + b.y + bb.y)),
              f2bf(kScale * (a.z + b.z + bb.z)), f2bf(kScale * (a.w + b.w + bb.w))};
    *(bf16x4*)(outA + (long)row * En + e) = oa;
}

// dst[c][r] = bf16(src[r][c]); src is [R][C] f32. grid(ceil(C/32), ceil(R/32), Z), block(32,8)
__global__ void transpose_f32_bf16(const float* __restrict__ src, __hip_bfloat16* __restrict__ dst,
                                   int R, int C, long sZi, long sZo) {
    __shared__ float tile[32][33];
    src += (long)blockIdx.z * sZi;
    dst += (long)blockIdx.z * sZo;
    int c0 = blockIdx.x * 32, r0 = blockIdx.y * 32;
    for (int i = threadIdx.y; i < 32; i += 8) {
        int r = r0 + i, c = c0 + threadIdx.x;
        tile[i][threadIdx.x] = (r < R && c < C) ? src[(long)r * C + c] : 0.f;
    }
    __syncthreads();
    for (int i = threadIdx.y; i < 32; i += 8) {
        int c = c0 + i, r = r0 + threadIdx.x;
        if (c < C && r < R) dst[(long)c * R + r] = f2bf(tile[threadIdx.x][i]);
    }
}

// f32 -> bf16 convert with scale (n divisible by 4)
__global__ void convert_bf16_kernel(const float* __restrict__ src, __hip_bfloat16* __restrict__ dst,
                                    long n4, float sc) {
    long i = (long)blockIdx.x * blockDim.x + threadIdx.x;
    if (i >= n4) return;
    long j = i * 4;
    float4 v = *(const float4*)(src + j);
    bf16x4 o{f2bf(v.x * sc), f2bf(v.y * sc), f2bf(v.z * sc), f2bf(v.w * sc)};
    *(bf16x4*)(dst + j) = o;
}

// conv weight pack for layer lbase+blockIdx.z, a/g interleaved in 16-col blocks:
// packed col c: grp=c>>5, w=c&31; o = w<16 ? grp*16+w : H + grp*16 + (w-16)
// wp[z*zstride + c][tap*H+i] = bf16(conv_w[l][o][i][tap]).  grid(12, 2048, nl), block 256.
__global__ void wpack_kernel(const float* __restrict__ convw, __hip_bfloat16* __restrict__ wp,
                             int lbase, long zstride) {
    int kk = blockIdx.x * 256 + threadIdx.x;  // 0..3071
    int c = blockIdx.y;                        // 0..2047 packed col
    int l = lbase + blockIdx.z;
    int grp = c >> 5, w = c & 31;
    int o = (w < 16) ? grp * 16 + w : Hn + grp * 16 + (w - 16);
    int i = kk & (Hn - 1);
    int tap = kk >> 10;
    long base = ((long)(l * 2 * Hn + o)) * (Hn * 3);
    wp[(long)blockIdx.z * zstride + (long)c * (3 * Hn) + kk] = f2bf(convw[base + (long)i * 3 + tap]);
}

// row softmax over S=512; writes bf16 (next GEMM input) + optional f32 (final attention)
__global__ __launch_bounds__(256) void softmax_kernel(const float* __restrict__ energy,
                                                      float* __restrict__ attn_f32,
                                                      __hip_bfloat16* __restrict__ attn_bf) {
    int row = blockIdx.x;  // 0..8191
    const float* e = energy + (long)row * Sn;
    int tid = threadIdx.x;
    float v0 = e[tid], v1 = e[tid + 256];
    float m = fmaxf(v0, v1);
    for (int off = 32; off; off >>= 1) m = fmaxf(m, __shfl_xor(m, off));
    __shared__ float redm[4];
    __shared__ float reds[4];
    int lane = tid & 63, w = tid >> 6;
    if (lane == 0) redm[w] = m;
    __syncthreads();
    m = fmaxf(fmaxf(redm[0], redm[1]), fmaxf(redm[2], redm[3]));
    float x0 = __expf(v0 - m), x1 = __expf(v1 - m);
    float s = x0 + x1;
    for (int off = 32; off; off >>= 1) s += __shfl_xor(s, off);
    if (lane == 0) reds[w] = s;
    __syncthreads();
    s = reds[0] + reds[1] + reds[2] + reds[3];
    float inv = 1.f / s;
    long base = (long)row * Sn;
    if (attn_f32) {
        attn_f32[base + tid] = x0 * inv;
        attn_f32[base + tid + 256] = x1 * inv;
    }
    attn_bf[base + tid] = f2bf(x0 * inv);
    attn_bf[base + tid + 256] = f2bf(x1 * inv);
}

// ---------------- 128x128 2-phase GEMM ----------------
// C[M,N] = A[M,K] @ Bw[N,K]^T.  EPI: 0: x=acc+bias; 2: x=((acc+bias+R1)*s1+R2)*s2;
// 3: x=acc*s1 + R1f[idx].  R1/R2/R1f batch-offset by z*cZ.
template <int EPI, bool OUTF32, bool NBOUND>
__global__ __launch_bounds__(256) void gemm_bf16(
    const __hip_bfloat16* __restrict__ A, const __hip_bfloat16* __restrict__ Bw,
    const float* __restrict__ bias, void* __restrict__ Cout,
    const __hip_bfloat16* __restrict__ R1, const __hip_bfloat16* __restrict__ R2,
    const float* __restrict__ R1f, const __hip_bfloat16* __restrict__ padrow,
    int M, int N, int K, long aZ, long bZ, long cZ, float s1, float s2) {
    __shared__ alignas(16) short As[2][128 * 32];
    __shared__ alignas(16) short Bs[2][128 * 32];
    const int tid = threadIdx.x;
    const int lane = tid & 63;
    const int wid = tid >> 6;
    const int wr = wid >> 1, wc = wid & 1;
    const int m0 = blockIdx.y * 128, n0 = blockIdx.x * 128;
    const short* Ag = (const short*)A + (long)blockIdx.z * aZ;
    const short* Bg = (const short*)Bw + (long)blockIdx.z * bZ;
    const short* pad = (const short*)padrow;

    f32x4 acc[4][4] = {};

    const int rc = tid >> 2;
    const int k8 = (tid & 3) * 8;

    auto stage = [&](int buf, int k0) {
#pragma unroll
        for (int j = 0; j < 2; ++j) {
            int r = rc + j * 64;
            const short* asrc = Ag + (long)(m0 + r) * K + k0 + k8;
            gload_lds16(asrc, &As[buf][r * 32 + k8]);
            int n = n0 + r;
            const short* bsrc = (NBOUND && n >= N) ? (pad + k8) : (Bg + (long)n * K + k0 + k8);
            gload_lds16(bsrc, &Bs[buf][r * 32 + k8]);
        }
    };

    stage(0, 0);
    __syncthreads();

    int cur = 0;
    for (int k0 = 0; k0 < K; k0 += 32) {
        if (k0 + 32 < K) stage(cur ^ 1, k0 + 32);
        const int rsel = lane & 15, hi = (lane >> 4) * 8;
        short8 af[4], bg[4];
#pragma unroll
        for (int mi = 0; mi < 4; ++mi)
            af[mi] = *(const short8*)&As[cur][(wr * 64 + mi * 16 + rsel) * 32 + hi];
#pragma unroll
        for (int ni = 0; ni < 4; ++ni)
            bg[ni] = *(const short8*)&Bs[cur][(wc * 64 + ni * 16 + rsel) * 32 + hi];
#pragma unroll
        for (int mi = 0; mi < 4; ++mi)
#pragma unroll
            for (int ni = 0; ni < 4; ++ni)
                acc[mi][ni] = __builtin_amdgcn_mfma_f32_16x16x32_bf16(af[mi], bg[ni], acc[mi][ni], 0, 0, 0);
        __syncthreads();
        cur ^= 1;
    }

    const int rsel = lane & 15, rg = (lane >> 4) * 4;
    float* Cf = (float*)Cout + (long)blockIdx.z * cZ;
    __hip_bfloat16* Cb = (__hip_bfloat16*)Cout + (long)blockIdx.z * cZ;
    const __hip_bfloat16* R1z = R1 + (long)blockIdx.z * cZ;
    const __hip_bfloat16* R2z = R2 + (long)blockIdx.z * cZ;
    const float* R1fz = R1f + (long)blockIdx.z * cZ;
#pragma unroll
    for (int ni = 0; ni < 4; ++ni) {
        int col = n0 + wc * 64 + ni * 16 + rsel;
        if (NBOUND && col >= N) continue;
        float bi = (EPI != 3 && bias) ? bias[col] : 0.f;
#pragma unroll
        for (int mi = 0; mi < 4; ++mi) {
            int row = m0 + wr * 64 + mi * 16 + rg;
            f32x4 v = acc[mi][ni];
#pragma unroll
            for (int q = 0; q < 4; ++q) {
                long idx = (long)(row + q) * N + col;
                float x;
                if (EPI == 3) x = v[q] * s1 + R1fz[idx];
                else {
                    x = v[q] + bi;
                    if (EPI >= 1) x = (x + bf2f(R1z[idx])) * s1;
                    if (EPI >= 2) x = (x + bf2f(R2z[idx])) * s2;
                }
                if (OUTF32) Cf[idx] = x;
                else Cb[idx] = f2bf(x);
            }
        }
    }
}

// ---------------- 256x256 deep-pipeline GEMM (conv + fc_out) ----------------
// T1 XCD-swizzle + T2 LDS-swizzle (both-sides involution) + T3/T4 counted vmcnt(8)
// double-buffer + T5 setprio. 8 waves (2Mx4N), BK=64. Dedup'd fragment reads
// (24 ds_read_b128 / wave / K-tile). GLUE: fused GLU epilogue.
template <bool OUTF32, bool GLUE, bool IM2COL, bool NBOUND>
__global__ __launch_bounds__(512, 2) void gemm256(
    const __hip_bfloat16* __restrict__ A, const __hip_bfloat16* __restrict__ Bw,
    const float* __restrict__ bias, void* __restrict__ Cout,
    const __hip_bfloat16* __restrict__ padrow, int M, int N, int K) {
    __shared__ alignas(16) short As[2][256 * 64];
    __shared__ alignas(16) short Bs[2][256 * 64];
    const int tid = threadIdx.x;
    const int lane = tid & 63;
    const int wid = tid >> 6;
    const int wr = wid >> 2, wc = wid & 3;
    const int nwg = gridDim.x * gridDim.y;
    const int orig = blockIdx.y * gridDim.x + blockIdx.x;
    const int qd = nwg >> 3, rd = nwg & 7, xc = orig & 7, loc = orig >> 3;
    const int bid = (xc < rd ? xc * (qd + 1) : rd * (qd + 1) + (xc - rd) * qd) + loc;
    const int n0 = (bid % gridDim.x) * 256, m0 = (bid / gridDim.x) * 256;
    const short* Ag = (const short*)A;
    const short* Bg = (const short*)Bw;
    const short* pad = (const short*)padrow;

    f32x4 acc[8][4] = {};

    const int srow_l = tid >> 3;
    const int scol = ((tid & 7) ^ (srow_l & 7)) * 8;
    const int sdst = (tid >> 3) * 64 + (tid & 7) * 8;

    auto stage = [&](int buf, int kt) {
        const int k0 = kt * 64;
#pragma unroll
        for (int j = 0; j < 4; ++j) {
            const int row = j * 64 + srow_l;
            const short* asrc;
            if (IM2COL) {
                int m = m0 + row;
                int t = m & (Tn - 1);
                int tap = k0 >> 10;
                int tau = t - 2 + tap;
                int kcol = (k0 & (Hn - 1)) + scol;
                asrc = (tau >= 0) ? (Ag + (long)(m - 2 + tap) * Hn + kcol) : (pad + scol);
            } else {
                asrc = Ag + (long)(m0 + row) * K + k0 + scol;
            }
            gload_lds16(asrc, &As[buf][j * 4096 + sdst]);
            int n = n0 + row;
            const short* bsrc = (NBOUND && n >= N) ? (pad + scol) : (Bg + (long)n * K + k0 + scol);
            gload_lds16(bsrc, &Bs[buf][j * 4096 + sdst]);
        }
    };

    const int rsel = lane & 15, hi = (lane >> 4) * 8;
    const int xorc = (rsel & 7) << 3;

    stage(0, 0);
    const int NT = K >> 6;
    for (int t = 0; t < NT; ++t) {
        const int cur = t & 1;
        if (t + 1 < NT) {
            stage(cur ^ 1, t + 1);
            asm volatile("s_waitcnt vmcnt(8)" ::: "memory");
        } else {
            asm volatile("s_waitcnt vmcnt(0)" ::: "memory");
        }
        __builtin_amdgcn_s_barrier();
        __builtin_amdgcn_sched_barrier(0);
        short8 bg[2][2][2];
#pragma unroll
        for (int nh = 0; nh < 2; ++nh)
#pragma unroll
            for (int i = 0; i < 2; ++i) {
                const int row = wc * 64 + nh * 32 + i * 16 + rsel;
#pragma unroll
                for (int ks = 0; ks < 2; ++ks)
                    bg[nh][i][ks] = *(const short8*)&Bs[cur][row * 64 + ((ks * 32 + hi) ^ xorc)];
            }
#pragma unroll
        for (int mh = 0; mh < 2; ++mh) {
            short8 af[4][2];
#pragma unroll
            for (int i = 0; i < 4; ++i) {
                const int row = wr * 128 + mh * 64 + i * 16 + rsel;
#pragma unroll
                for (int ks = 0; ks < 2; ++ks)
                    af[i][ks] = *(const short8*)&As[cur][row * 64 + ((ks * 32 + hi) ^ xorc)];
            }
            __builtin_amdgcn_s_setprio(1);
#pragma unroll
            for (int nh = 0; nh < 2; ++nh)
#pragma unroll
                for (int i = 0; i < 4; ++i)
#pragma unroll
                    for (int jn = 0; jn < 2; ++jn)
#pragma unroll
                        for (int ks = 0; ks < 2; ++ks)
                            acc[mh * 4 + i][nh * 2 + jn] = __builtin_amdgcn_mfma_f32_16x16x32_bf16(
                                af[i][ks], bg[nh][jn][ks], acc[mh * 4 + i][nh * 2 + jn], 0, 0, 0);
            __builtin_amdgcn_s_setprio(0);
            __builtin_amdgcn_sched_barrier(0);
        }
        __builtin_amdgcn_s_barrier();
        __builtin_amdgcn_sched_barrier(0);
    }

    const int rg = (lane >> 4) * 4;
    if (GLUE) {
        __hip_bfloat16* Cb = (__hip_bfloat16*)Cout;
        const int No = N >> 1;
#pragma unroll
        for (int p = 0; p < 2; ++p) {
            int jcol = ((n0 + wc * 64) >> 1) + p * 16 + rsel;
            float ba = bias[jcol];
            float bgv = bias[Hn + jcol];
#pragma unroll
            for (int mi = 0; mi < 8; ++mi) {
                int row = m0 + wr * 128 + mi * 16 + rg;
                f32x4 va = acc[mi][2 * p], vg = acc[mi][2 * p + 1];
#pragma unroll
                for (int q = 0; q < 4; ++q) {
                    float a = va[q] + ba;
                    float g = vg[q] + bgv;
                    Cb[(long)(row + q) * No + jcol] = f2bf(a * (1.f / (1.f + __expf(-g))));
                }
            }
        }
        return;
    }
    float* Cf = (float*)Cout;
    __hip_bfloat16* Cb = (__hip_bfloat16*)Cout;
#pragma unroll
    for (int ni = 0; ni < 4; ++ni) {
        int col = n0 + wc * 64 + ni * 16 + rsel;
        if (NBOUND && col >= N) continue;
        float bi = bias ? bias[col] : 0.f;
#pragma unroll
        for (int mi = 0; mi < 8; ++mi) {
            int row = m0 + wr * 128 + mi * 16 + rg;
            f32x4 v = acc[mi][ni];
#pragma unroll
            for (int q = 0; q < 4; ++q) {
                long idx = (long)(row + q) * N + col;
                float x = v[q] + bi;
                if (OUTF32) Cf[idx] = x;
                else Cb[idx] = f2bf(x);
            }
        }
    }
}

// ---------------- launcher ----------------

extern "C" void kernel_launch(void* const* d_in, const int* in_sizes, int n_in,
                              void* d_out, int out_size, void* d_ws, size_t ws_size,
                              hipStream_t stream) {
    const int* tgt = (const int*)d_in[0];
    const float* enc_conved = (const float*)d_in[1];
    const float* enc_combined = (const float*)d_in[2];
    const float* tok_emb = (const float*)d_in[3];
    const float* pos_emb = (const float*)d_in[4];
    const float* w_e2h = (const float*)d_in[5];
    const float* b_e2h = (const float*)d_in[6];
    const float* w_h2e = (const float*)d_in[7];
    const float* b_h2e = (const float*)d_in[8];
    const float* w_ah2e = (const float*)d_in[9];
    const float* b_ah2e = (const float*)d_in[10];
    const float* w_ae2h = (const float*)d_in[11];
    const float* b_ae2h = (const float*)d_in[12];
    const float* w_fc = (const float*)d_in[13];
    const float* b_fc = (const float*)d_in[14];
    const float* conv_w = (const float*)d_in[15];
    const float* conv_b = (const float*)d_in[16];

    char* ws = (char*)d_ws;
    size_t off = 0;
    auto alloc = [&](size_t bytes) { size_t r = off; off = (off + bytes + 255) & ~(size_t)255; return r; };
    __hip_bfloat16* emb    = (__hip_bfloat16*)(ws + alloc((size_t)Mn * En * 2));
    __hip_bfloat16* embA   = (__hip_bfloat16*)(ws + alloc((size_t)Mn * En * 2));
    __hip_bfloat16* convin = (__hip_bfloat16*)(ws + alloc((size_t)Mn * Hn * 2));
    __hip_bfloat16* conved = (__hip_bfloat16*)(ws + alloc((size_t)Mn * Hn * 2));
    size_t o_en = alloc((size_t)Mn * Sn * 4);
    float* energy = (float*)(ws + o_en);
    __hip_bfloat16* encm = (__hip_bfloat16*)(ws + o_en);   // overlay: prep-only bf16(enc_combined)
    __hip_bfloat16* attnbf = (__hip_bfloat16*)(ws + alloc((size_t)Mn * Sn * 2));
    __hip_bfloat16* wT_e2h = (__hip_bfloat16*)(ws + alloc((size_t)Hn * En * 2));
    __hip_bfloat16* wT_h2e = (__hip_bfloat16*)(ws + alloc((size_t)En * Hn * 2));
    __hip_bfloat16* wT_ae2h= (__hip_bfloat16*)(ws + alloc((size_t)Hn * En * 2));
    __hip_bfloat16* wbAH   = (__hip_bfloat16*)(ws + alloc((size_t)Hn * En * 2));   // w_ah2e bf16 [H,E]
    __hip_bfloat16* wT_fc  = (__hip_bfloat16*)(ws + alloc((size_t)Vn * En * 2));
    __hip_bfloat16* encc   = (__hip_bfloat16*)(ws + alloc((size_t)Bn * Sn * En * 2));
    __hip_bfloat16* encAH  = (__hip_bfloat16*)(ws + alloc((size_t)Bn * Sn * Hn * 2));
    __hip_bfloat16* encCW  = (__hip_bfloat16*)(ws + alloc((size_t)Bn * Hn * Sn * 2));
    float* embE            = (float*)(ws + alloc((size_t)Mn * Sn * 4));
    __hip_bfloat16* padrow = (__hip_bfloat16*)(ws + alloc(256));
    // wpack last: all-6-layers if workspace allows, else single-layer reused
    const size_t W1 = (size_t)2 * Hn * 3 * Hn * 2;   // 12.6 MB per layer
    bool packAll = (off + 6 * W1 + 256 <= ws_size);
    __hip_bfloat16* wpack = (__hip_bfloat16*)(ws + alloc(packAll ? 6 * W1 : W1));
    __hip_bfloat16* tmpE = conved;  // overlay: conved dead after last update GEMM

    float* out = (float*)d_out;
    float* attn_out = out + (long)Mn * Vn;
    const long bSq = (long)Sn * Sn;
    const long bSH = (long)Sn * Hn;

    dim3 tb(32, 8);
    const __hip_bfloat16* nb = nullptr;
    const float* nf = nullptr;

    // ---- prep ----
    padfill_kernel<<<1, 128, 0, stream>>>(padrow);
    embed_kernel<<<Mn, 128, 0, stream>>>(tgt, tok_emb, pos_emb, b_ah2e, emb, embA);
    transpose_f32_bf16<<<dim3(Hn / 32, En / 32, 1), tb, 0, stream>>>(w_e2h, wT_e2h, En, Hn, 0, 0);
    transpose_f32_bf16<<<dim3(En / 32, Hn / 32, 1), tb, 0, stream>>>(w_h2e, wT_h2e, Hn, En, 0, 0);
    transpose_f32_bf16<<<dim3(Hn / 32, En / 32, 1), tb, 0, stream>>>(w_ae2h, wT_ae2h, En, Hn, 0, 0);
    transpose_f32_bf16<<<dim3((Vn + 31) / 32, En / 32, 1), tb, 0, stream>>>(w_fc, wT_fc, En, Vn, 0, 0);
    convert_bf16_kernel<<<((long)Hn * En / 4 + 255) / 256, 256, 0, stream>>>(w_ah2e, wbAH, (long)Hn * En / 4, 1.f);
    convert_bf16_kernel<<<((long)Bn * Sn * En / 4 + 255) / 256, 256, 0, stream>>>(enc_conved, encc, (long)Bn * Sn * En / 4, 1.f);
    convert_bf16_kernel<<<((long)Bn * Sn * En / 4 + 255) / 256, 256, 0, stream>>>(enc_combined, encm, (long)Bn * Sn * En / 4, 1.f);
    if (packAll)
        wpack_kernel<<<dim3(3 * Hn / 256, 2 * Hn, Ln), 256, 0, stream>>>(conv_w, wpack, 0, (long)2 * Hn * 3 * Hn);

    // encAH[b][s][h] = encc[b] @ w_ah2e^T   (layer-invariant attention factor)
    gemm_bf16<0, false, false><<<dim3(Hn / 128, Sn / 128, Bn), 256, 0, stream>>>(
        encc, wbAH, nullptr, encAH, nb, nb, nf, padrow, Sn, Hn, En, bSq, 0, bSH, 1.f, 1.f);
    // encCW[b][h][s] = (enc_combined[b] @ w_ae2h)^T
    gemm_bf16<0, false, false><<<dim3(Sn / 128, Hn / 128, Bn), 256, 0, stream>>>(
        wT_ae2h, encm, nullptr, encCW, nb, nb, nf, padrow, Hn, Sn, En, 0, bSq, bSH, 1.f, 1.f);
    // embE[b][t][s] = embA[b] @ encc[b]^T   (f32; kScale folded into embA)
    gemm_bf16<0, true, false><<<dim3(Sn / 128, Tn / 128, Bn), 256, 0, stream>>>(
        embA, encc, nullptr, embE, nb, nb, nf, padrow, Tn, Sn, En, bSq, bSq, bSq, 1.f, 1.f);
    // conv_input = embedded @ emb2hid + b       [8192,1024]
    gemm_bf16<0, false, false><<<dim3(Hn / 128, Mn / 128, 1), 256, 0, stream>>>(
        emb, wT_e2h, b_e2h, convin, nb, nb, nf, padrow, Mn, Hn, En, 0, 0, 0, 1.f, 1.f);

    for (int l = 0; l < Ln; ++l) {
        __hip_bfloat16* wpl = wpack + (packAll ? (size_t)l * (2 * Hn) * (3 * Hn) : 0);
        if (!packAll)
            wpack_kernel<<<dim3(3 * Hn / 256, 2 * Hn, 1), 256, 0, stream>>>(conv_w, wpack, l, 0);
        // conved = GLU(im2col(conv_input) @ wpack^T + conv_b[l])   [8192,1024] fused
        gemm256<false, true, true, false><<<dim3(2 * Hn / 256, Mn / 256, 1), 512, 0, stream>>>(
            convin, wpl, conv_b + (long)l * 2 * Hn, conved, padrow, Mn, 2 * Hn, 3 * Hn);
        // energy[b] = kScale * conved[b] @ encAH[b]^T(B-layout) + embE[b]   (f32)
        gemm_bf16<3, true, false><<<dim3(Sn / 128, Tn / 128, Bn), 256, 0, stream>>>(
            conved, encAH, nullptr, energy, nb, nb, embE, padrow,
            Tn, Sn, Hn, (long)Tn * Hn, bSH, bSq, kScale, 1.f);
        // attention = softmax(energy)  (f32 out only needed from the LAST layer)
        softmax_kernel<<<Mn, 256, 0, stream>>>(energy, (l == Ln - 1) ? attn_out : nullptr, attnbf);
        // conv_input = ((attn @ encCW + b_ae2h + conved)*s + conv_input)*s
        gemm_bf16<2, false, false><<<dim3(Hn / 128, Tn / 128, Bn), 256, 0, stream>>>(
            attnbf, encCW, b_ae2h, convin, conved, convin, nf, padrow,
            Tn, Hn, Sn, bSq, bSH, (long)Tn * Hn, kScale, kScale);
    }

    // conved = conv_input @ hid2emb + b   [8192,512]  (tmpE overlays conved)
    gemm_bf16<0, false, false><<<dim3(En / 128, Mn / 128, 1), 256, 0, stream>>>(
        convin, wT_h2e, b_h2e, tmpE, nb, nb, nf, padrow, Mn, En, Hn, 0, 0, 0, 1.f, 1.f);
    // output = conved @ fc_out + b        [8192,10000] f32, N-bounded  (256² pipeline)
    gemm256<true, false, false, true><<<dim3((Vn + 255) / 256, Mn / 256, 1), 512, 0, stream>>>(
        tmpE, wT_fc, b_fc, out, padrow, Mn, Vn, En);
}

// Round 9
// 1321.365 us; speedup vs baseline: 1.2621x; 1.1321x over previous
//
#include <hip/hip_runtime.h>
#include <hip/hip_bf16.h>

typedef __attribute__((ext_vector_type(4))) float f32x4;
typedef __attribute__((ext_vector_type(8))) short short8;

#define DEVFN __device__ __forceinline__

static constexpr int Bn = 16, Tn = 512, Sn = 512, Vn = 10000, En = 512, Hn = 1024, Ln = 6;
static constexpr int Mn = Bn * Tn;  // 8192 token rows
static constexpr float kScale = 0.70710678118654752440f;

DEVFN float bf2f(__hip_bfloat16 x) { return __bfloat162float(x); }
DEVFN __hip_bfloat16 f2bf(float x) { return __float2bfloat16(x); }

struct bf16x4 { __hip_bfloat16 x, y, z, w; };

// async global -> LDS, 16B per lane (wave-uniform LDS base + lane*16 layout)
DEVFN void gload_lds16(const short* g, short* l) {
    __builtin_amdgcn_global_load_lds((const __attribute__((address_space(1))) void*)g,
                                     (__attribute__((address_space(3))) void*)l, 16, 0, 0);
}

// ---------------- small prep kernels ----------------

__global__ void padfill_kernel(__hip_bfloat16* p) {
    p[threadIdx.x] = f2bf(1.0f);  // PAD_VAL as float, per torch code
}

// embedded[b,t,:] = tok_emb[tgt[b,t],:] + pos_emb[t,:]  (bf16)
// embA = kScale*(embedded + b_ah2e)                      (bf16, for embE precompute)
__global__ void embed_kernel(const int* __restrict__ tgt, const float* __restrict__ tok,
                             const float* __restrict__ pos, const float* __restrict__ bah,
                             __hip_bfloat16* __restrict__ out, __hip_bfloat16* __restrict__ outA) {
    int row = blockIdx.x;              // 0..8191
    int t = row & (Tn - 1);
    int v = tgt[row];
    const float* tr = tok + (long)v * En;
    const float* pr = pos + (long)t * En;
    int e = threadIdx.x * 4;           // block 128 covers 512
    float4 a = *(const float4*)(tr + e);
    float4 b = *(const float4*)(pr + e);
    float4 bb = *(const float4*)(bah + e);
    bf16x4 o{f2bf(a.x + b.x), f2bf(a.y + b.y), f2bf(a.z + b.z), f2bf(a.w + b.w)};
    *(bf16x4*)(out + (long)row * En + e) = o;
    bf16x4 oa{f2bf(kScale * (a.x + b.x + bb.x)), f2bf(kScale * (a.y + b.y + bb.y)),
              f2bf(kScale * (a.z + b.z + bb.z)), f2bf(kScale * (a.w + b.w + bb.w))};
    *(bf16x4*)(outA + (long)row * En + e) = oa;
}

// dst[c][r] = bf16(src[r][c]); src is [R][C] f32. grid(ceil(C/32), ceil(R/32), Z), block(32,8)
__global__ void transpose_f32_bf16(const float* __restrict__ src, __hip_bfloat16* __restrict__ dst,
                                   int R, int C, long sZi, long sZo) {
    __shared__ float tile[32][33];
    src += (long)blockIdx.z * sZi;
    dst += (long)blockIdx.z * sZo;
    int c0 = blockIdx.x * 32, r0 = blockIdx.y * 32;
    for (int i = threadIdx.y; i < 32; i += 8) {
        int r = r0 + i, c = c0 + threadIdx.x;
        tile[i][threadIdx.x] = (r < R && c < C) ? src[(long)r * C + c] : 0.f;
    }
    __syncthreads();
    for (int i = threadIdx.y; i < 32; i += 8) {
        int c = c0 + i, r = r0 + threadIdx.x;
        if (c < C && r < R) dst[(long)c * R + r] = f2bf(tile[threadIdx.x][i]);
    }
}

// f32 -> bf16 convert (n divisible by 4)
__global__ void convert_bf16_kernel(const float* __restrict__ src, __hip_bfloat16* __restrict__ dst,
                                    long n4) {
    long i = (long)blockIdx.x * blockDim.x + threadIdx.x;
    if (i >= n4) return;
    long j = i * 4;
    float4 v = *(const float4*)(src + j);
    bf16x4 o{f2bf(v.x), f2bf(v.y), f2bf(v.z), f2bf(v.w)};
    *(bf16x4*)(dst + j) = o;
}

// Coalesced conv-weight pack for layer l, a/g interleaved in 16-col blocks for fused GLU.
// One block per packed output row c (grid 2048): coalesced float4 read of the 3072-f32
// source row into LDS, stride-3 gather (3 coprime 32 -> no systematic bank conflict),
// coalesced bf16x4 writes.  wp[c][tap*H+i] = bf16(conv_w[l][o(c)][i][tap]).
__global__ __launch_bounds__(256) void wpack2_kernel(const float* __restrict__ convw,
                                                     __hip_bfloat16* __restrict__ wp, int l) {
    __shared__ float row[3 * Hn];
    int c = blockIdx.x;                        // 0..2047 packed col
    int grp = c >> 5, w = c & 31;
    int o = (w < 16) ? grp * 16 + w : Hn + grp * 16 + (w - 16);
    const float* src = convw + ((long)(l * 2 * Hn + o)) * (Hn * 3);
#pragma unroll
    for (int j = 0; j < 3; ++j) {
        int idx = (j * 256 + threadIdx.x) * 4;
        *(float4*)&row[idx] = *(const float4*)(src + idx);
    }
    __syncthreads();
    __hip_bfloat16* dst = wp + (long)c * (3 * Hn);
#pragma unroll
    for (int j = 0; j < 3; ++j) {
        int kk = (j * 256 + threadIdx.x) * 4;   // 4-chunk never crosses a tap boundary (1024%4==0)
        int tap = kk >> 10;
        int i = kk & (Hn - 1);
        bf16x4 v{f2bf(row[i * 3 + tap]), f2bf(row[(i + 1) * 3 + tap]),
                 f2bf(row[(i + 2) * 3 + tap]), f2bf(row[(i + 3) * 3 + tap])};
        *(bf16x4*)(dst + kk) = v;
    }
}

// row softmax over S=512; writes bf16 (next GEMM input) + optional f32 (final attention)
__global__ __launch_bounds__(256) void softmax_kernel(const float* __restrict__ energy,
                                                      float* __restrict__ attn_f32,
                                                      __hip_bfloat16* __restrict__ attn_bf) {
    int row = blockIdx.x;  // 0..8191
    const float* e = energy + (long)row * Sn;
    int tid = threadIdx.x;
    float v0 = e[tid], v1 = e[tid + 256];
    float m = fmaxf(v0, v1);
    for (int off = 32; off; off >>= 1) m = fmaxf(m, __shfl_xor(m, off));
    __shared__ float redm[4];
    __shared__ float reds[4];
    int lane = tid & 63, w = tid >> 6;
    if (lane == 0) redm[w] = m;
    __syncthreads();
    m = fmaxf(fmaxf(redm[0], redm[1]), fmaxf(redm[2], redm[3]));
    float x0 = __expf(v0 - m), x1 = __expf(v1 - m);
    float s = x0 + x1;
    for (int off = 32; off; off >>= 1) s += __shfl_xor(s, off);
    if (lane == 0) reds[w] = s;
    __syncthreads();
    s = reds[0] + reds[1] + reds[2] + reds[3];
    float inv = 1.f / s;
    long base = (long)row * Sn;
    if (attn_f32) {
        attn_f32[base + tid] = x0 * inv;
        attn_f32[base + tid + 256] = x1 * inv;
    }
    attn_bf[base + tid] = f2bf(x0 * inv);
    attn_bf[base + tid + 256] = f2bf(x1 * inv);
}

// ---------------- 128x128 2-phase GEMM ----------------
// C[M,N] = A[M,K] @ Bw[N,K]^T.  EPI: 0: x=acc+bias; 2: x=((acc+bias+R1)*s1+R2)*s2;
// 3: x=acc*s1 + R1f[idx].  R1/R2/R1f batch-offset by z*cZ.
template <int EPI, bool OUTF32, bool NBOUND>
__global__ __launch_bounds__(256) void gemm_bf16(
    const __hip_bfloat16* __restrict__ A, const __hip_bfloat16* __restrict__ Bw,
    const float* __restrict__ bias, void* __restrict__ Cout,
    const __hip_bfloat16* __restrict__ R1, const __hip_bfloat16* __restrict__ R2,
    const float* __restrict__ R1f, const __hip_bfloat16* __restrict__ padrow,
    int M, int N, int K, long aZ, long bZ, long cZ, float s1, float s2) {
    __shared__ alignas(16) short As[2][128 * 32];
    __shared__ alignas(16) short Bs[2][128 * 32];
    const int tid = threadIdx.x;
    const int lane = tid & 63;
    const int wid = tid >> 6;
    const int wr = wid >> 1, wc = wid & 1;
    const int m0 = blockIdx.y * 128, n0 = blockIdx.x * 128;
    const short* Ag = (const short*)A + (long)blockIdx.z * aZ;
    const short* Bg = (const short*)Bw + (long)blockIdx.z * bZ;
    const short* pad = (const short*)padrow;

    f32x4 acc[4][4] = {};

    const int rc = tid >> 2;
    const int k8 = (tid & 3) * 8;

    auto stage = [&](int buf, int k0) {
#pragma unroll
        for (int j = 0; j < 2; ++j) {
            int r = rc + j * 64;
            const short* asrc = Ag + (long)(m0 + r) * K + k0 + k8;
            gload_lds16(asrc, &As[buf][r * 32 + k8]);
            int n = n0 + r;
            const short* bsrc = (NBOUND && n >= N) ? (pad + k8) : (Bg + (long)n * K + k0 + k8);
            gload_lds16(bsrc, &Bs[buf][r * 32 + k8]);
        }
    };

    stage(0, 0);
    __syncthreads();

    int cur = 0;
    for (int k0 = 0; k0 < K; k0 += 32) {
        if (k0 + 32 < K) stage(cur ^ 1, k0 + 32);
        const int rsel = lane & 15, hi = (lane >> 4) * 8;
        short8 af[4], bg[4];
#pragma unroll
        for (int mi = 0; mi < 4; ++mi)
            af[mi] = *(const short8*)&As[cur][(wr * 64 + mi * 16 + rsel) * 32 + hi];
#pragma unroll
        for (int ni = 0; ni < 4; ++ni)
            bg[ni] = *(const short8*)&Bs[cur][(wc * 64 + ni * 16 + rsel) * 32 + hi];
#pragma unroll
        for (int mi = 0; mi < 4; ++mi)
#pragma unroll
            for (int ni = 0; ni < 4; ++ni)
                acc[mi][ni] = __builtin_amdgcn_mfma_f32_16x16x32_bf16(af[mi], bg[ni], acc[mi][ni], 0, 0, 0);
        __syncthreads();
        cur ^= 1;
    }

    const int rsel = lane & 15, rg = (lane >> 4) * 4;
    float* Cf = (float*)Cout + (long)blockIdx.z * cZ;
    __hip_bfloat16* Cb = (__hip_bfloat16*)Cout + (long)blockIdx.z * cZ;
    const __hip_bfloat16* R1z = R1 + (long)blockIdx.z * cZ;
    const __hip_bfloat16* R2z = R2 + (long)blockIdx.z * cZ;
    const float* R1fz = R1f + (long)blockIdx.z * cZ;
#pragma unroll
    for (int ni = 0; ni < 4; ++ni) {
        int col = n0 + wc * 64 + ni * 16 + rsel;
        if (NBOUND && col >= N) continue;
        float bi = (EPI != 3 && bias) ? bias[col] : 0.f;
#pragma unroll
        for (int mi = 0; mi < 4; ++mi) {
            int row = m0 + wr * 64 + mi * 16 + rg;
            f32x4 v = acc[mi][ni];
#pragma unroll
            for (int q = 0; q < 4; ++q) {
                long idx = (long)(row + q) * N + col;
                float x;
                if (EPI == 3) x = v[q] * s1 + R1fz[idx];
                else {
                    x = v[q] + bi;
                    if (EPI >= 1) x = (x + bf2f(R1z[idx])) * s1;
                    if (EPI >= 2) x = (x + bf2f(R2z[idx])) * s2;
                }
                if (OUTF32) Cf[idx] = x;
                else Cb[idx] = f2bf(x);
            }
        }
    }
}

// ---------------- 256x256 deep-pipeline GEMM (conv + fc_out) ----------------
// T1 XCD-swizzle + T2 LDS-swizzle (both-sides involution) + T3/T4 counted vmcnt(8)
// double-buffer + T5 setprio. 8 waves (2Mx4N), BK=64. Dedup'd fragment reads
// (24 ds_read_b128 / wave / K-tile). GLUE: fused GLU epilogue.
template <bool OUTF32, bool GLUE, bool IM2COL, bool NBOUND>
__global__ __launch_bounds__(512, 2) void gemm256(
    const __hip_bfloat16* __restrict__ A, const __hip_bfloat16* __restrict__ Bw,
    const float* __restrict__ bias, void* __restrict__ Cout,
    const __hip_bfloat16* __restrict__ padrow, int M, int N, int K) {
    __shared__ alignas(16) short As[2][256 * 64];
    __shared__ alignas(16) short Bs[2][256 * 64];
    const int tid = threadIdx.x;
    const int lane = tid & 63;
    const int wid = tid >> 6;
    const int wr = wid >> 2, wc = wid & 3;
    const int nwg = gridDim.x * gridDim.y;
    const int orig = blockIdx.y * gridDim.x + blockIdx.x;
    const int qd = nwg >> 3, rd = nwg & 7, xc = orig & 7, loc = orig >> 3;
    const int bid = (xc < rd ? xc * (qd + 1) : rd * (qd + 1) + (xc - rd) * qd) + loc;
    const int n0 = (bid % gridDim.x) * 256, m0 = (bid / gridDim.x) * 256;
    const short* Ag = (const short*)A;
    const short* Bg = (const short*)Bw;
    const short* pad = (const short*)padrow;

    f32x4 acc[8][4] = {};

    const int srow_l = tid >> 3;
    const int scol = ((tid & 7) ^ (srow_l & 7)) * 8;
    const int sdst = (tid >> 3) * 64 + (tid & 7) * 8;

    auto stage = [&](int buf, int kt) {
        const int k0 = kt * 64;
#pragma unroll
        for (int j = 0; j < 4; ++j) {
            const int row = j * 64 + srow_l;
            const short* asrc;
            if (IM2COL) {
                int m = m0 + row;
                int t = m & (Tn - 1);
                int tap = k0 >> 10;
                int tau = t - 2 + tap;
                int kcol = (k0 & (Hn - 1)) + scol;
                asrc = (tau >= 0) ? (Ag + (long)(m - 2 + tap) * Hn + kcol) : (pad + scol);
            } else {
                asrc = Ag + (long)(m0 + row) * K + k0 + scol;
            }
            gload_lds16(asrc, &As[buf][j * 4096 + sdst]);
            int n = n0 + row;
            const short* bsrc = (NBOUND && n >= N) ? (pad + scol) : (Bg + (long)n * K + k0 + scol);
            gload_lds16(bsrc, &Bs[buf][j * 4096 + sdst]);
        }
    };

    const int rsel = lane & 15, hi = (lane >> 4) * 8;
    const int xorc = (rsel & 7) << 3;

    stage(0, 0);
    const int NT = K >> 6;
    for (int t = 0; t < NT; ++t) {
        const int cur = t & 1;
        if (t + 1 < NT) {
            stage(cur ^ 1, t + 1);
            asm volatile("s_waitcnt vmcnt(8)" ::: "memory");
        } else {
            asm volatile("s_waitcnt vmcnt(0)" ::: "memory");
        }
        __builtin_amdgcn_s_barrier();
        __builtin_amdgcn_sched_barrier(0);
        short8 bg[2][2][2];
#pragma unroll
        for (int nh = 0; nh < 2; ++nh)
#pragma unroll
            for (int i = 0; i < 2; ++i) {
                const int row = wc * 64 + nh * 32 + i * 16 + rsel;
#pragma unroll
                for (int ks = 0; ks < 2; ++ks)
                    bg[nh][i][ks] = *(const short8*)&Bs[cur][row * 64 + ((ks * 32 + hi) ^ xorc)];
            }
#pragma unroll
        for (int mh = 0; mh < 2; ++mh) {
            short8 af[4][2];
#pragma unroll
            for (int i = 0; i < 4; ++i) {
                const int row = wr * 128 + mh * 64 + i * 16 + rsel;
#pragma unroll
                for (int ks = 0; ks < 2; ++ks)
                    af[i][ks] = *(const short8*)&As[cur][row * 64 + ((ks * 32 + hi) ^ xorc)];
            }
            __builtin_amdgcn_s_setprio(1);
#pragma unroll
            for (int nh = 0; nh < 2; ++nh)
#pragma unroll
                for (int i = 0; i < 4; ++i)
#pragma unroll
                    for (int jn = 0; jn < 2; ++jn)
#pragma unroll
                        for (int ks = 0; ks < 2; ++ks)
                            acc[mh * 4 + i][nh * 2 + jn] = __builtin_amdgcn_mfma_f32_16x16x32_bf16(
                                af[i][ks], bg[nh][jn][ks], acc[mh * 4 + i][nh * 2 + jn], 0, 0, 0);
            __builtin_amdgcn_s_setprio(0);
            __builtin_amdgcn_sched_barrier(0);
        }
        __builtin_amdgcn_s_barrier();
        __builtin_amdgcn_sched_barrier(0);
    }

    const int rg = (lane >> 4) * 4;
    if (GLUE) {
        __hip_bfloat16* Cb = (__hip_bfloat16*)Cout;
        const int No = N >> 1;
#pragma unroll
        for (int p = 0; p < 2; ++p) {
            int jcol = ((n0 + wc * 64) >> 1) + p * 16 + rsel;
            float ba = bias[jcol];
            float bgv = bias[Hn + jcol];
#pragma unroll
            for (int mi = 0; mi < 8; ++mi) {
                int row = m0 + wr * 128 + mi * 16 + rg;
                f32x4 va = acc[mi][2 * p], vg = acc[mi][2 * p + 1];
#pragma unroll
                for (int q = 0; q < 4; ++q) {
                    float a = va[q] + ba;
                    float g = vg[q] + bgv;
                    Cb[(long)(row + q) * No + jcol] = f2bf(a * (1.f / (1.f + __expf(-g))));
                }
            }
        }
        return;
    }
    float* Cf = (float*)Cout;
    __hip_bfloat16* Cb = (__hip_bfloat16*)Cout;
#pragma unroll
    for (int ni = 0; ni < 4; ++ni) {
        int col = n0 + wc * 64 + ni * 16 + rsel;
        if (NBOUND && col >= N) continue;
        float bi = bias ? bias[col] : 0.f;
#pragma unroll
        for (int mi = 0; mi < 8; ++mi) {
            int row = m0 + wr * 128 + mi * 16 + rg;
            f32x4 v = acc[mi][ni];
#pragma unroll
            for (int q = 0; q < 4; ++q) {
                long idx = (long)(row + q) * N + col;
                float x = v[q] + bi;
                if (OUTF32) Cf[idx] = x;
                else Cb[idx] = f2bf(x);
            }
        }
    }
}

// ---------------- launcher ----------------

extern "C" void kernel_launch(void* const* d_in, const int* in_sizes, int n_in,
                              void* d_out, int out_size, void* d_ws, size_t ws_size,
                              hipStream_t stream) {
    const int* tgt = (const int*)d_in[0];
    const float* enc_conved = (const float*)d_in[1];
    const float* enc_combined = (const float*)d_in[2];
    const float* tok_emb = (const float*)d_in[3];
    const float* pos_emb = (const float*)d_in[4];
    const float* w_e2h = (const float*)d_in[5];
    const float* b_e2h = (const float*)d_in[6];
    const float* w_h2e = (const float*)d_in[7];
    const float* b_h2e = (const float*)d_in[8];
    const float* w_ah2e = (const float*)d_in[9];
    const float* b_ah2e = (const float*)d_in[10];
    const float* w_ae2h = (const float*)d_in[11];
    const float* b_ae2h = (const float*)d_in[12];
    const float* w_fc = (const float*)d_in[13];
    const float* b_fc = (const float*)d_in[14];
    const float* conv_w = (const float*)d_in[15];
    const float* conv_b = (const float*)d_in[16];

    char* ws = (char*)d_ws;
    size_t off = 0;
    auto alloc = [&](size_t bytes) { size_t r = off; off = (off + bytes + 255) & ~(size_t)255; return r; };
    __hip_bfloat16* emb    = (__hip_bfloat16*)(ws + alloc((size_t)Mn * En * 2));
    __hip_bfloat16* embA   = (__hip_bfloat16*)(ws + alloc((size_t)Mn * En * 2));
    __hip_bfloat16* convin = (__hip_bfloat16*)(ws + alloc((size_t)Mn * Hn * 2));
    __hip_bfloat16* conved = (__hip_bfloat16*)(ws + alloc((size_t)Mn * Hn * 2));
    size_t o_en = alloc((size_t)Mn * Sn * 4);
    float* energy = (float*)(ws + o_en);
    __hip_bfloat16* encm = (__hip_bfloat16*)(ws + o_en);   // overlay: prep-only bf16(enc_combined)
    __hip_bfloat16* attnbf = (__hip_bfloat16*)(ws + alloc((size_t)Mn * Sn * 2));
    __hip_bfloat16* wT_e2h = (__hip_bfloat16*)(ws + alloc((size_t)Hn * En * 2));
    __hip_bfloat16* wT_h2e = (__hip_bfloat16*)(ws + alloc((size_t)En * Hn * 2));
    __hip_bfloat16* wT_ae2h= (__hip_bfloat16*)(ws + alloc((size_t)Hn * En * 2));
    __hip_bfloat16* wbAH   = (__hip_bfloat16*)(ws + alloc((size_t)Hn * En * 2));   // w_ah2e bf16 [H,E]
    __hip_bfloat16* wT_fc  = (__hip_bfloat16*)(ws + alloc((size_t)Vn * En * 2));
    __hip_bfloat16* encc   = (__hip_bfloat16*)(ws + alloc((size_t)Bn * Sn * En * 2));
    __hip_bfloat16* encAH  = (__hip_bfloat16*)(ws + alloc((size_t)Bn * Sn * Hn * 2));
    __hip_bfloat16* encCW  = (__hip_bfloat16*)(ws + alloc((size_t)Bn * Hn * Sn * 2));
    float* embE            = (float*)(ws + alloc((size_t)Mn * Sn * 4));
    __hip_bfloat16* padrow = (__hip_bfloat16*)(ws + alloc(256));
    __hip_bfloat16* wpack  = (__hip_bfloat16*)(ws + alloc((size_t)2 * Hn * 3 * Hn * 2)); // per-layer, warm
    __hip_bfloat16* tmpE = conved;  // overlay: conved dead after last update GEMM

    float* out = (float*)d_out;
    float* attn_out = out + (long)Mn * Vn;
    const long bSq = (long)Sn * Sn;
    const long bSH = (long)Sn * Hn;

    dim3 tb(32, 8);
    const __hip_bfloat16* nb = nullptr;
    const float* nf = nullptr;

    // ---- prep ----
    padfill_kernel<<<1, 128, 0, stream>>>(padrow);
    embed_kernel<<<Mn, 128, 0, stream>>>(tgt, tok_emb, pos_emb, b_ah2e, emb, embA);
    transpose_f32_bf16<<<dim3(Hn / 32, En / 32, 1), tb, 0, stream>>>(w_e2h, wT_e2h, En, Hn, 0, 0);
    transpose_f32_bf16<<<dim3(En / 32, Hn / 32, 1), tb, 0, stream>>>(w_h2e, wT_h2e, Hn, En, 0, 0);
    transpose_f32_bf16<<<dim3(Hn / 32, En / 32, 1), tb, 0, stream>>>(w_ae2h, wT_ae2h, En, Hn, 0, 0);
    transpose_f32_bf16<<<dim3((Vn + 31) / 32, En / 32, 1), tb, 0, stream>>>(w_fc, wT_fc, En, Vn, 0, 0);
    convert_bf16_kernel<<<((long)Hn * En / 4 + 255) / 256, 256, 0, stream>>>(w_ah2e, wbAH, (long)Hn * En / 4);
    convert_bf16_kernel<<<((long)Bn * Sn * En / 4 + 255) / 256, 256, 0, stream>>>(enc_conved, encc, (long)Bn * Sn * En / 4);
    convert_bf16_kernel<<<((long)Bn * Sn * En / 4 + 255) / 256, 256, 0, stream>>>(enc_combined, encm, (long)Bn * Sn * En / 4);

    // encAH[b][s][h] = encc[b] @ w_ah2e^T   (layer-invariant attention factor)
    gemm_bf16<0, false, false><<<dim3(Hn / 128, Sn / 128, Bn), 256, 0, stream>>>(
        encc, wbAH, nullptr, encAH, nb, nb, nf, padrow, Sn, Hn, En, bSq, 0, bSH, 1.f, 1.f);
    // encCW[b][h][s] = (enc_combined[b] @ w_ae2h)^T
    gemm_bf16<0, false, false><<<dim3(Sn / 128, Hn / 128, Bn), 256, 0, stream>>>(
        wT_ae2h, encm, nullptr, encCW, nb, nb, nf, padrow, Hn, Sn, En, 0, bSq, bSH, 1.f, 1.f);
    // embE[b][t][s] = embA[b] @ encc[b]^T   (f32; kScale folded into embA)
    gemm_bf16<0, true, false><<<dim3(Sn / 128, Tn / 128, Bn), 256, 0, stream>>>(
        embA, encc, nullptr, embE, nb, nb, nf, padrow, Tn, Sn, En, bSq, bSq, bSq, 1.f, 1.f);
    // conv_input = embedded @ emb2hid + b       [8192,1024]
    gemm_bf16<0, false, false><<<dim3(Hn / 128, Mn / 128, 1), 256, 0, stream>>>(
        emb, wT_e2h, b_e2h, convin, nb, nb, nf, padrow, Mn, Hn, En, 0, 0, 0, 1.f, 1.f);

    for (int l = 0; l < Ln; ++l) {
        // pack conv weight for THIS layer just before use (keeps B-panel L2/L3-warm)
        wpack2_kernel<<<2 * Hn, 256, 0, stream>>>(conv_w, wpack, l);
        // conved = GLU(im2col(conv_input) @ wpack^T + conv_b[l])   [8192,1024] fused
        gemm256<false, true, true, false><<<dim3(2 * Hn / 256, Mn / 256, 1), 512, 0, stream>>>(
            convin, wpack, conv_b + (long)l * 2 * Hn, conved, padrow, Mn, 2 * Hn, 3 * Hn);
        // energy[b] = kScale * conved[b] @ encAH[b]^T(B-layout) + embE[b]   (f32)
        gemm_bf16<3, true, false><<<dim3(Sn / 128, Tn / 128, Bn), 256, 0, stream>>>(
            conved, encAH, nullptr, energy, nb, nb, embE, padrow,
            Tn, Sn, Hn, (long)Tn * Hn, bSH, bSq, kScale, 1.f);
        // attention = softmax(energy)  (f32 out only needed from the LAST layer)
        softmax_kernel<<<Mn, 256, 0, stream>>>(energy, (l == Ln - 1) ? attn_out : nullptr, attnbf);
        // conv_input = ((attn @ encCW + b_ae2h + conved)*s + conv_input)*s
        gemm_bf16<2, false, false><<<dim3(Hn / 128, Tn / 128, Bn), 256, 0, stream>>>(
            attnbf, encCW, b_ae2h, convin, conved, convin, nf, padrow,
            Tn, Hn, Sn, bSq, bSH, (long)Tn * Hn, kScale, kScale);
    }

    // conved = conv_input @ hid2emb + b   [8192,512]  (tmpE overlays conved)
    gemm_bf16<0, false, false><<<dim3(En / 128, Mn / 128, 1), 256, 0, stream>>>(
        convin, wT_h2e, b_h2e, tmpE, nb, nb, nf, padrow, Mn, En, Hn, 0, 0, 0, 1.f, 1.f);
    // output = conved @ fc_out + b        [8192,10000] f32, N-bounded  (256² pipeline)
    gemm256<true, false, false, true><<<dim3((Vn + 255) / 256, Mn / 256, 1), 512, 0, stream>>>(
        tmpE, wT_fc, b_fc, out, padrow, Mn, Vn, En);
}